// Round 2
// baseline (116.816 us; speedup 1.0000x reference)
//
#include <hip/hip_runtime.h>

// GPDGaussian: per-pixel 629x3 conv -> (m, S=R^T diag(s) R, s)
// 7 pixels per 256-thread block; thread t -> (pixel q=t/34, row m=t%34).
// R rows in registers, 561 Givens rotations fully unrolled.
// One LDS buffer, phase-overlaid: cos/sin -> V -> S staging.

#define CCH 34          // s/m channels
#define ACH 561         // rotation angles = 34*33/2
#define HWPIX 4096      // 64*64
#define NPIX 16384      // 4*64*64
#define PXB 7           // pixels per block
#define NTHR 256
#define VSTR 35         // V row stride (floats): bank = 3m%32, conflict-free
#define BUF_FLOATS (PXB * CCH * VSTR)   // 8330 >= max(cs 7854, S 8092)

// output offsets (floats)
#define OFF_S 557056        // 16384*34
#define OFF_s 19496960      // 557056 + 16384*1156

__global__ __launch_bounds__(NTHR) void gpd_kernel(
    const float* __restrict__ x,     // (4,3,64,64)
    const float* __restrict__ Wm,    // (629,3)
    const float* __restrict__ bvec,  // (629,)
    float* __restrict__ out)
{
    __shared__ alignas(16) float buf[BUF_FLOATS];
    __shared__ float lds_rsp[PXB * CCH];     // sqrt(s)

    const int t   = threadIdx.x;
    const int p0  = blockIdx.x * PXB;
    const int npx = min(PXB, NPIX - p0);

    const float LOG2E = 1.4426950408889634f;

    // ---- Phase A: 1x1 conv + activations, flat over npx*629 channels ----
    float2* csbuf = (float2*)buf;            // [PXB*ACH] (cos,sin)
    for (int o = t; o < npx * 629; o += NTHR) {
        const int q  = (int)((unsigned)o / 629u);   // compiler magic div
        const int ch = o - q * 629;
        const int p  = p0 + q;
        const int b  = p >> 12;
        const int hw = p & 4095;
        const float x0 = x[(b * 3 + 0) * HWPIX + hw];
        const float x1 = x[(b * 3 + 1) * HWPIX + hw];
        const float x2 = x[(b * 3 + 2) * HWPIX + hw];
        float wv = fmaf(Wm[ch * 3 + 0], x0,
                   fmaf(Wm[ch * 3 + 1], x1, Wm[ch * 3 + 2] * x2)) + bvec[ch];
        if (ch < CCH) {
            out[(size_t)p * CCH + ch] = wv;                       // mean
        } else if (ch < 2 * CCH) {
            float e  = __builtin_amdgcn_exp2f(-wv * LOG2E);
            float sg = __builtin_amdgcn_rcpf(1.0f + e);
            float sv = fmaf(999.999f, sg, 0.001f);                // s
            int c = ch - CCH;
            out[OFF_s + ((size_t)(b * CCH + c)) * HWPIX + hw] = sv;
            lds_rsp[q * CCH + c] = __builtin_amdgcn_sqrtf(sv);
        } else {
            // angle = pi*tanh(wv); HW cos/sin take revolutions: tanh(wv)/2
            float e  = __builtin_amdgcn_exp2f((2.0f * LOG2E) * wv);
            float tt = 1.0f - 2.0f * __builtin_amdgcn_rcpf(e + 1.0f);
            float rev = 0.5f * tt;
            csbuf[q * ACH + (ch - 2 * CCH)] =
                make_float2(__builtin_amdgcn_cosf(rev), __builtin_amdgcn_sinf(rev));
        }
    }
    __syncthreads();

    const int q = t / CCH;                   // pixel within block
    const int m = t - q * CCH;               // R row owned by this lane
    const bool act = (t < npx * CCH);

    // ---- Phase B: 561 Givens rotations on register-resident row m ----
    float R[CCH];
    float rs = 0.0f;
    if (act) {
        #pragma unroll
        for (int k = 0; k < CCH; ++k) R[k] = (k == m) ? 1.0f : 0.0f;
        const float2* cs = csbuf + q * ACH;
        int pidx = 0;
        #pragma unroll
        for (int i = 0; i < CCH - 1; ++i) {
            #pragma unroll
            for (int j = i + 1; j < CCH; ++j) {
                float2 c = cs[pidx++];       // <=3 distinct addrs per wave
                float ri = R[i], rj = R[j];
                R[i] = fmaf(c.x, ri,  c.y * rj);
                R[j] = fmaf(c.x, rj, -c.y * ri);
            }
        }
        rs = lds_rsp[t];                     // q*CCH + m == t
    }
    __syncthreads();                         // all cs reads done

    // V = diag(sqrt(s)) * R  -> overlay onto cs region
    if (act) {
        float* V = buf + q * (CCH * VSTR);
        #pragma unroll
        for (int n = 0; n < CCH; ++n) V[m * VSTR + n] = rs * R[n];
    }
    __syncthreads();

    // ---- Phase C: S = V^T V ; lane computes S row m of its pixel ----
    float acc[CCH];
    if (act) {
        const float* V = buf + q * (CCH * VSTR);
        #pragma unroll
        for (int n = 0; n < CCH; ++n) acc[n] = 0.0f;
        for (int mm = 0; mm < CCH; ++mm) {   // rolled: runtime LDS addrs ok
            float vk = V[mm * VSTR + m];     // conflict-free (stride 35)
            #pragma unroll
            for (int n = 0; n < CCH; ++n)
                acc[n] = fmaf(vk, V[mm * VSTR + n], acc[n]);
        }
    }
    __syncthreads();                         // all V reads done

    if (act) {
        float* Sst = buf + q * (CCH * CCH);  // overlay S staging
        #pragma unroll
        for (int n = 0; n < CCH; ++n) Sst[m * CCH + n] = acc[n];
    }
    __syncthreads();

    // ---- coalesced float4 copy-out of S (npx*289 float4) ----
    {
        const float4* s4 = (const float4*)buf;
        float4* o4 = (float4*)(out + OFF_S + (size_t)p0 * (CCH * CCH));
        const int n4 = npx * (CCH * CCH / 4);
        for (int e = t; e < n4; e += NTHR) o4[e] = s4[e];
    }
}

extern "C" void kernel_launch(void* const* d_in, const int* in_sizes, int n_in,
                              void* d_out, int out_size, void* d_ws, size_t ws_size,
                              hipStream_t stream) {
    const float* x  = (const float*)d_in[0];
    const float* W  = (const float*)d_in[1];
    const float* bv = (const float*)d_in[2];
    float* out = (float*)d_out;
    const int nblk = (NPIX + PXB - 1) / PXB;   // 2341
    hipLaunchKernelGGL(gpd_kernel, dim3(nblk), dim3(NTHR), 0, stream,
                       x, W, bv, out);
}

// Round 3
// 101.374 us; speedup vs baseline: 1.1523x; 1.1523x over previous
//
#include <hip/hip_runtime.h>

// GPDGaussian: per-pixel 629x3 conv -> (m, S=R^T diag(s) R, s)
// 7 pixels / 256-thread block; thread t -> (pixel q=t/34, row m=t%34).
// Phase A/B chunked: cos/sin for 280|281 angles in LDS, applied, overwritten.
// Phase C: R stored in LDS as f16 pairs along m; S row via v_dot2_f32_f16;
// direct contiguous global stores of S (no staging).

#define CCH 34
#define ACH 561
#define HWPIX 4096
#define NPIX 16384
#define PXB 7
#define NTHR 256
#define CH0 280            // chunk split: [0,280) and [280,561)
#define CSTR 282           // csbuf per-pixel stride (float2), 16B-aligned
#define RPROW 36           // Rp row stride in dwords (144B, 16B-aligned)
#define RPPX (17 * RPROW)  // 612 dwords per pixel
#define OFF_S 557056
#define OFF_s 19496960
#define LOG2E 1.4426950408889634f

typedef _Float16 h2 __attribute__((ext_vector_type(2)));

struct Pairs {
    short i[ACH]; short j[ACH];
    constexpr Pairs() : i(), j() {
        int p = 0;
        for (int a = 0; a < CCH - 1; ++a)
            for (int b = a + 1; b < CCH; ++b) { i[p] = (short)a; j[p] = (short)b; ++p; }
    }
};
__device__ constexpr Pairs PR{};

__device__ __forceinline__ float dot2h(h2 a, h2 b, float c) {
#if __has_builtin(__builtin_amdgcn_fdot2)
    return __builtin_amdgcn_fdot2(a, b, c, false);
#else
    return fmaf((float)a[0], (float)b[0], fmaf((float)a[1], (float)b[1], c));
#endif
}

__device__ __forceinline__ void rot(float* R, int i, int j, float c, float s) {
    float ri = R[i], rj = R[j];
    R[i] = fmaf(c, ri,  s * rj);
    R[j] = fmaf(c, rj, -s * ri);
}

template <int P0, int P1>
__device__ __forceinline__ void apply_rots(float* R, const float2* cs) {
    constexpr int N = P1 - P0;
    #pragma unroll
    for (int k = 0; k + 1 < N; k += 2) {
        float4 cc = *(const float4*)(cs + k);      // 16B: two (c,s) pairs
        rot(R, PR.i[P0 + k],     PR.j[P0 + k],     cc.x, cc.y);
        rot(R, PR.i[P0 + k + 1], PR.j[P0 + k + 1], cc.z, cc.w);
    }
    if constexpr (N & 1) {
        float2 c1 = cs[N - 1];
        rot(R, PR.i[P1 - 1], PR.j[P1 - 1], c1.x, c1.y);
    }
}

__device__ __forceinline__ float convw(const float* __restrict__ Wm,
                                       const float* __restrict__ bvec, int ch,
                                       float x0, float x1, float x2) {
    return fmaf(Wm[ch * 3 + 0], x0,
           fmaf(Wm[ch * 3 + 1], x1, Wm[ch * 3 + 2] * x2)) + bvec[ch];
}

template <int G0, int G1>
__device__ __forceinline__ void fill_cs(const float* __restrict__ x,
                                        const float* __restrict__ Wm,
                                        const float* __restrict__ bvec,
                                        float2* csbuf, int p0, int npx, int t) {
    constexpr int LEN = G1 - G0;
    for (int o = t; o < npx * LEN; o += NTHR) {
        int q = (int)((unsigned)o / (unsigned)LEN);
        int l = o - q * LEN;
        int p = p0 + q, b = p >> 12, hw = p & 4095;
        float x0 = x[(b * 3 + 0) * HWPIX + hw];
        float x1 = x[(b * 3 + 1) * HWPIX + hw];
        float x2 = x[(b * 3 + 2) * HWPIX + hw];
        float wv = convw(Wm, bvec, 2 * CCH + G0 + l, x0, x1, x2);
        // angle = pi*tanh(wv); HW cos/sin take revolutions: tanh(wv)/2
        float e  = __builtin_amdgcn_exp2f((2.0f * LOG2E) * wv);
        float tt = 1.0f - 2.0f * __builtin_amdgcn_rcpf(e + 1.0f);
        float rev = 0.5f * tt;
        csbuf[q * CSTR + l] = make_float2(__builtin_amdgcn_cosf(rev),
                                          __builtin_amdgcn_sinf(rev));
    }
}

__global__ __launch_bounds__(NTHR) void gpd_kernel(
    const float* __restrict__ x,     // (4,3,64,64)
    const float* __restrict__ Wm,    // (629,3)
    const float* __restrict__ bvec,  // (629,)
    float* __restrict__ out)
{
    __shared__ alignas(16) char ldsbuf[PXB * RPPX * 4];   // 17136 B (cs | Rp)
    __shared__ alignas(4) _Float16 lds_sh[PXB * CCH];     // s in f16, 476 B

    const int t   = threadIdx.x;
    const int p0  = blockIdx.x * PXB;
    const int npx = min(PXB, NPIX - p0);
    float2* csbuf = (float2*)ldsbuf;

    // ---- A1: mean + s channels (68 per pixel) ----
    for (int o = t; o < npx * 68; o += NTHR) {
        int q = (int)((unsigned)o / 68u);
        int ch = o - q * 68;
        int p = p0 + q, b = p >> 12, hw = p & 4095;
        float x0 = x[(b * 3 + 0) * HWPIX + hw];
        float x1 = x[(b * 3 + 1) * HWPIX + hw];
        float x2 = x[(b * 3 + 2) * HWPIX + hw];
        float wv = convw(Wm, bvec, ch, x0, x1, x2);
        if (ch < CCH) {
            out[(size_t)p * CCH + ch] = wv;                      // mean
        } else {
            float e  = __builtin_amdgcn_exp2f(-wv * LOG2E);
            float sg = __builtin_amdgcn_rcpf(1.0f + e);
            float sv = fmaf(999.999f, sg, 0.001f);               // s
            int c = ch - CCH;
            out[OFF_s + (size_t)(b * CCH + c) * HWPIX + hw] = sv;
            lds_sh[q * CCH + c] = (_Float16)sv;
        }
    }

    const int q = t / CCH;
    const int m = t - q * CCH;
    const bool act = (t < npx * CCH);

    float R[CCH];
    #pragma unroll
    for (int k = 0; k < CCH; ++k) R[k] = (k == m) ? 1.0f : 0.0f;

    // ---- chunk 0: fill cos/sin for angles [0,280), apply ----
    fill_cs<0, CH0>(x, Wm, bvec, csbuf, p0, npx, t);
    __syncthreads();
    if (act) apply_rots<0, CH0>(R, csbuf + q * CSTR);
    __syncthreads();

    // ---- chunk 1: angles [280,561) ----
    fill_cs<CH0, ACH>(x, Wm, bvec, csbuf, p0, npx, t);
    __syncthreads();
    if (act) apply_rots<CH0, ACH>(R, csbuf + q * CSTR);
    __syncthreads();

    // ---- store R as f16 pair-layout (pairs along m), overlaying csbuf ----
    if (act) {
        _Float16* dst = (_Float16*)(ldsbuf + (size_t)q * RPPX * 4
                                    + (m >> 1) * RPROW * 4 + (m & 1) * 2);
        #pragma unroll
        for (int n = 0; n < CCH; ++n) dst[2 * n] = (_Float16)R[n];
    }
    __syncthreads();

    // ---- phase C: S row m = sum_mp dot2( s-pair * Rcol_m-pair, Rrow-pairs ) ----
    if (act) {
        const unsigned int* px = (const unsigned int*)(ldsbuf + (size_t)q * RPPX * 4);
        const _Float16* sh = lds_sh + q * CCH;
        float acc[CCH];
        #pragma unroll
        for (int n = 0; n < CCH; ++n) acc[n] = 0.0f;

        for (int mp = 0; mp < 17; ++mp) {
            const unsigned int* row = px + mp * RPROW;
            h2 vk = __builtin_bit_cast(h2, row[m]) * *(const h2*)(sh + 2 * mp);
            #pragma unroll
            for (int g = 0; g < 8; ++g) {
                uint4 rr = *(const uint4*)(row + 4 * g);
                acc[4*g+0] = dot2h(vk, __builtin_bit_cast(h2, rr.x), acc[4*g+0]);
                acc[4*g+1] = dot2h(vk, __builtin_bit_cast(h2, rr.y), acc[4*g+1]);
                acc[4*g+2] = dot2h(vk, __builtin_bit_cast(h2, rr.z), acc[4*g+2]);
                acc[4*g+3] = dot2h(vk, __builtin_bit_cast(h2, rr.w), acc[4*g+3]);
            }
            uint2 rr2 = *(const uint2*)(row + 32);
            acc[32] = dot2h(vk, __builtin_bit_cast(h2, rr2.x), acc[32]);
            acc[33] = dot2h(vk, __builtin_bit_cast(h2, rr2.y), acc[33]);
        }

        // direct store of S row m (contiguous 136B per thread; wave covers
        // a dense region so L2 merges to full lines)
        float* os = out + OFF_S + (size_t)(p0 + q) * (CCH * CCH) + m * CCH;
        #pragma unroll
        for (int n2 = 0; n2 < 17; ++n2) {
            float2 v; v.x = acc[2 * n2]; v.y = acc[2 * n2 + 1];
            *(float2*)(os + 2 * n2) = v;
        }
    }
}

extern "C" void kernel_launch(void* const* d_in, const int* in_sizes, int n_in,
                              void* d_out, int out_size, void* d_ws, size_t ws_size,
                              hipStream_t stream) {
    const float* x  = (const float*)d_in[0];
    const float* W  = (const float*)d_in[1];
    const float* bv = (const float*)d_in[2];
    float* out = (float*)d_out;
    const int nblk = (NPIX + PXB - 1) / PXB;   // 2341
    hipLaunchKernelGGL(gpd_kernel, dim3(nblk), dim3(NTHR), 0, stream,
                       x, W, bv, out);
}

// Round 5
// 78.598 us; speedup vs baseline: 1.4863x; 1.2898x over previous
//
#include <hip/hip_runtime.h>

// GPDGaussian: per-pixel 629x3 conv -> (m, S=R^T diag(s) R, s)
// 14 pixels / 256-thread block as 7 PAIRS; thread t -> (pair pr=t/34, row m=t%34).
// Rotations in packed f32 (v_pk_fma_f32): R2[n] = {pixelA, pixelB} per thread.
// cs cells {cA,cB,sA,sB} written as one ds_write_b128 per angle (conflict-free).
// Phase C: f16 pair-layout R + v_dot2_f32_f16, run for both pixels of the pair.

#define CCH 34
#define ACH 561
#define HWPIX 4096
#define NPIX 16384
#define PXB 14
#define NTHR 256
#define CH0 281                 // chunk split: [0,281) and [281,561)
#define CSPAIR (281 * 16)       // cs bytes per pair per chunk
#define VROW 36                 // V row stride in dwords (144B, 16B-aligned)
#define VPX (17 * VROW * 4)     // 2448 B per pixel V-region
#define OFF_S 557056
#define OFF_s 19496960
#define LOG2E 1.4426950408889634f

typedef float   f32x2 __attribute__((ext_vector_type(2)));
typedef _Float16 h2   __attribute__((ext_vector_type(2)));

struct Pairs {
    short i[ACH]; short j[ACH];
    constexpr Pairs() : i(), j() {
        int p = 0;
        for (int a = 0; a < CCH - 1; ++a)
            for (int b = a + 1; b < CCH; ++b) { i[p] = (short)a; j[p] = (short)b; ++p; }
    }
};
__device__ constexpr Pairs PR{};

__device__ __forceinline__ float dot2h(h2 a, h2 b, float c) {
#if __has_builtin(__builtin_amdgcn_fdot2)
    return __builtin_amdgcn_fdot2(a, b, c, false);
#else
    return fmaf((float)a[0], (float)b[0], fmaf((float)a[1], (float)b[1], c));
#endif
}

// Givens rotation on packed rows: Ri' = c*Ri + s*Rj ; Rj' = c*Rj - s*Ri
__device__ __forceinline__ void rot2(f32x2& Ri, f32x2& Rj, f32x2 c2, f32x2 s2) {
    f32x2 t1, t2;
    asm("v_pk_mul_f32 %0, %1, %2" : "=v"(t1) : "v"(s2), "v"(Rj));
    asm("v_pk_mul_f32 %0, %1, %2" : "=v"(t2) : "v"(s2), "v"(Ri));
    asm("v_pk_fma_f32 %0, %1, %2, %3" : "=v"(Ri) : "v"(c2), "v"(Ri), "v"(t1));
    asm("v_pk_fma_f32 %0, %1, %2, %3 neg_lo:[0,0,1] neg_hi:[0,0,1]"
        : "=v"(Rj) : "v"(c2), "v"(Rj), "v"(t2));
}

template <int P0, int P1>
__device__ __forceinline__ void apply_rots(f32x2* R2, const float4* cs) {
    #pragma unroll
    for (int k = P0; k < P1; ++k) {
        float4 cc = cs[k - P0];                 // broadcast b128 (<=2 addrs/wave)
        f32x2 c2; c2[0] = cc.x; c2[1] = cc.y;
        f32x2 s2; s2[0] = cc.z; s2[1] = cc.w;
        rot2(R2[PR.i[k]], R2[PR.j[k]], c2, s2);
    }
}

__device__ __forceinline__ float2 cs_of(float wv) {
    // angle = pi*tanh(wv); HW cos/sin take revolutions: tanh(wv)/2
    float e  = __builtin_amdgcn_exp2f((2.0f * LOG2E) * wv);
    float tt = 1.0f - 2.0f * __builtin_amdgcn_rcpf(e + 1.0f);
    float rv = 0.5f * tt;
    return make_float2(__builtin_amdgcn_cosf(rv), __builtin_amdgcn_sinf(rv));
}

// one thread computes BOTH pixels of its pair for angle l -> one b128 write
template <int G0, int LEN>
__device__ __forceinline__ void fill_cs(const float* __restrict__ Wm,
                                        const float* __restrict__ bvec,
                                        const float* xs, char* ldsbuf,
                                        int npr, int npx, int t) {
    for (int o = t; o < npr * LEN; o += NTHR) {
        int pr = (int)((unsigned)o / (unsigned)LEN);
        int l  = o - pr * LEN;
        int ch = 2 * CCH + G0 + l;
        float w0 = Wm[ch * 3 + 0], w1 = Wm[ch * 3 + 1], w2 = Wm[ch * 3 + 2];
        float bb = bvec[ch];
        int pa = 2 * pr;
        int pb = (2 * pr + 1 < npx) ? (2 * pr + 1) : pa;
        float2 A = cs_of(fmaf(w0, xs[pa*3+0], fmaf(w1, xs[pa*3+1], w2 * xs[pa*3+2])) + bb);
        float2 B = cs_of(fmaf(w0, xs[pb*3+0], fmaf(w1, xs[pb*3+1], w2 * xs[pb*3+2])) + bb);
        float4 cell; cell.x = A.x; cell.y = B.x; cell.z = A.y; cell.w = B.y;
        *(float4*)(ldsbuf + pr * CSPAIR + l * 16) = cell;   // dense b128, no conflict
    }
}

__global__ __launch_bounds__(NTHR, 4) void gpd_kernel(
    const float* __restrict__ x,     // (4,3,64,64)
    const float* __restrict__ Wm,    // (629,3)
    const float* __restrict__ bvec,  // (629,)
    float* __restrict__ out)
{
    __shared__ alignas(16) char ldsbuf[PXB * VPX];     // 34272 B (cs | V-f16 overlay)
    __shared__ _Float16 lds_sh[PXB * CCH];             // s in f16
    __shared__ float xs[PXB * 3];

    const int t   = threadIdx.x;
    const int p0  = blockIdx.x * PXB;
    const int npx = min(PXB, NPIX - p0);
    const int npr = (npx + 1) >> 1;

    // ---- stage x into LDS ----
    for (int i = t; i < npx * 3; i += NTHR) {
        int px = (int)((unsigned)i / 3u); int c = i - px * 3;
        int p = p0 + px; int b = p >> 12; int hw = p & 4095;
        xs[i] = x[(b * 3 + c) * HWPIX + hw];
    }
    __syncthreads();

    // ---- A1: mean + s channels (reads xs; writes global + lds_sh) ----
    for (int o = t; o < npx * 68; o += NTHR) {
        int q = (int)((unsigned)o / 68u); int ch = o - q * 68;
        int p = p0 + q; int b = p >> 12; int hw = p & 4095;
        float wv = fmaf(Wm[ch*3+0], xs[q*3+0],
                   fmaf(Wm[ch*3+1], xs[q*3+1], Wm[ch*3+2] * xs[q*3+2])) + bvec[ch];
        if (ch < CCH) {
            out[(size_t)p * CCH + ch] = wv;                       // mean
        } else {
            float e  = __builtin_amdgcn_exp2f(-wv * LOG2E);
            float sg = __builtin_amdgcn_rcpf(1.0f + e);
            float sv = fmaf(999.999f, sg, 0.001f);                // s
            int c = ch - CCH;
            out[OFF_s + (size_t)(b * CCH + c) * HWPIX + hw] = sv;
            lds_sh[q * CCH + c] = (_Float16)sv;
        }
    }

    const int pr = t / CCH;
    const int m  = t - pr * CCH;
    const bool act = (t < npr * CCH);
    const bool hasB = act && (2 * pr + 1 < npx);

    f32x2 R2[CCH];
    #pragma unroll
    for (int k = 0; k < CCH; ++k) { R2[k][0] = (k == m) ? 1.0f : 0.0f; R2[k][1] = R2[k][0]; }

    // ---- chunk 0 ----
    fill_cs<0, CH0>(Wm, bvec, xs, ldsbuf, npr, npx, t);
    __syncthreads();
    if (act) apply_rots<0, CH0>(R2, (const float4*)(ldsbuf + pr * CSPAIR));
    __syncthreads();
    // ---- chunk 1 ----
    fill_cs<CH0, ACH - CH0>(Wm, bvec, xs, ldsbuf, npr, npx, t);
    __syncthreads();
    if (act) apply_rots<CH0, ACH>(R2, (const float4*)(ldsbuf + pr * CSPAIR));
    __syncthreads();

    // ---- store R as f16 pair-layout (rows 2mp,2mp+1 packed per dword) ----
    if (act) {
        char* baseA = ldsbuf + (2*pr)   * VPX + (m >> 1) * (VROW*4) + (m & 1) * 2;
        char* baseB = ldsbuf + (2*pr+1) * VPX + (m >> 1) * (VROW*4) + (m & 1) * 2;
        #pragma unroll
        for (int n = 0; n < CCH; ++n) {
#if __has_builtin(__builtin_amdgcn_cvt_pkrtz)
            h2 hv = __builtin_bit_cast(h2, __builtin_amdgcn_cvt_pkrtz(R2[n][0], R2[n][1]));
#else
            h2 hv; hv[0] = (_Float16)R2[n][0]; hv[1] = (_Float16)R2[n][1];
#endif
            *(_Float16*)(baseA + n * 4) = hv[0];
            if (hasB) *(_Float16*)(baseB + n * 4) = hv[1];
        }
    }
    __syncthreads();

    // ---- phase C: S row m for both pixels of the pair ----
    for (int hh = 0; hh < 2; ++hh) {
        int px = 2 * pr + hh;
        if (act && px < npx) {
            const unsigned* base = (const unsigned*)(ldsbuf + px * VPX);
            const _Float16* sh = lds_sh + px * CCH;
            float acc[CCH];
            #pragma unroll
            for (int n = 0; n < CCH; ++n) acc[n] = 0.0f;
            for (int mp = 0; mp < 17; ++mp) {
                const unsigned* row = base + mp * VROW;
                h2 vk = __builtin_bit_cast(h2, row[m]) * *(const h2*)(sh + 2 * mp);
                #pragma unroll
                for (int g = 0; g < 8; ++g) {
                    uint4 rr = *(const uint4*)(row + 4 * g);
                    acc[4*g+0] = dot2h(vk, __builtin_bit_cast(h2, rr.x), acc[4*g+0]);
                    acc[4*g+1] = dot2h(vk, __builtin_bit_cast(h2, rr.y), acc[4*g+1]);
                    acc[4*g+2] = dot2h(vk, __builtin_bit_cast(h2, rr.z), acc[4*g+2]);
                    acc[4*g+3] = dot2h(vk, __builtin_bit_cast(h2, rr.w), acc[4*g+3]);
                }
                uint2 rr2 = *(const uint2*)(row + 32);
                acc[32] = dot2h(vk, __builtin_bit_cast(h2, rr2.x), acc[32]);
                acc[33] = dot2h(vk, __builtin_bit_cast(h2, rr2.y), acc[33]);
            }
            float* os = out + OFF_S + (size_t)(p0 + px) * (CCH * CCH) + m * CCH;
            #pragma unroll
            for (int n2 = 0; n2 < 17; ++n2) {
                float2 v; v.x = acc[2*n2]; v.y = acc[2*n2+1];
                *(float2*)(os + 2 * n2) = v;
            }
        }
    }
}

extern "C" void kernel_launch(void* const* d_in, const int* in_sizes, int n_in,
                              void* d_out, int out_size, void* d_ws, size_t ws_size,
                              hipStream_t stream) {
    const float* x  = (const float*)d_in[0];
    const float* W  = (const float*)d_in[1];
    const float* bv = (const float*)d_in[2];
    float* out = (float*)d_out;
    const int nblk = (NPIX + PXB - 1) / PXB;   // 1171
    hipLaunchKernelGGL(gpd_kernel, dim3(nblk), dim3(NTHR), 0, stream,
                       x, W, bv, out);
}

// Round 6
// 74.793 us; speedup vs baseline: 1.5619x; 1.0509x over previous
//
#include <hip/hip_runtime.h>

// GPDGaussian: per-pixel 629x3 conv -> (m, S=R^T diag(s) R, s)
// 14 pixels / 256-thread block as 7 PAIRS; thread t -> (pair pr=t/34, row m=t%34).
// Rotations packed f32 (v_pk_fma_f32): R2[n] = {pixelA, pixelB}.
// cos/sin in 4 LDS chunks (<=141 angles); phase C in 2 rounds (A then B pixels)
// with V staged for 7 pixels at a time -> LDS ~18.3KB -> 5 blocks/CU.

#define CCH 34
#define ACH 561
#define HWPIX 4096
#define NPIX 16384
#define PXB 14
#define NPR 7
#define NTHR 256
#define CSLEN 141               // max angles per chunk
#define CSPAIR (CSLEN * 16)     // cs bytes per pair per chunk
#define VROW 36                 // V row stride in dwords (144B, 16B-aligned)
#define VPX (17 * VROW * 4)     // 2448 B per pixel V-region
#define OFF_S 557056
#define OFF_s 19496960
#define LOG2E 1.4426950408889634f

typedef float    f32x2 __attribute__((ext_vector_type(2)));
typedef _Float16 h2    __attribute__((ext_vector_type(2)));

struct Pairs {
    short i[ACH]; short j[ACH];
    constexpr Pairs() : i(), j() {
        int p = 0;
        for (int a = 0; a < CCH - 1; ++a)
            for (int b = a + 1; b < CCH; ++b) { i[p] = (short)a; j[p] = (short)b; ++p; }
    }
};
__device__ constexpr Pairs PR{};

__device__ __forceinline__ float dot2h(h2 a, h2 b, float c) {
#if __has_builtin(__builtin_amdgcn_fdot2)
    return __builtin_amdgcn_fdot2(a, b, c, false);
#else
    return fmaf((float)a[0], (float)b[0], fmaf((float)a[1], (float)b[1], c));
#endif
}

// Givens rotation on packed rows: Ri' = c*Ri + s*Rj ; Rj' = c*Rj - s*Ri
__device__ __forceinline__ void rot2(f32x2& Ri, f32x2& Rj, f32x2 c2, f32x2 s2) {
    f32x2 t1, t2;
    asm("v_pk_mul_f32 %0, %1, %2" : "=v"(t1) : "v"(s2), "v"(Rj));
    asm("v_pk_mul_f32 %0, %1, %2" : "=v"(t2) : "v"(s2), "v"(Ri));
    asm("v_pk_fma_f32 %0, %1, %2, %3" : "=v"(Ri) : "v"(c2), "v"(Ri), "v"(t1));
    asm("v_pk_fma_f32 %0, %1, %2, %3 neg_lo:[0,0,1] neg_hi:[0,0,1]"
        : "=v"(Rj) : "v"(c2), "v"(Rj), "v"(t2));
}

template <int P0, int P1>
__device__ __forceinline__ void apply_rots(f32x2* R2, const float4* cs) {
    #pragma unroll
    for (int k = P0; k < P1; ++k) {
        float4 cc = cs[k - P0];                 // broadcast b128 (<=2 addrs/wave)
        f32x2 c2; c2[0] = cc.x; c2[1] = cc.y;
        f32x2 s2; s2[0] = cc.z; s2[1] = cc.w;
        rot2(R2[PR.i[k]], R2[PR.j[k]], c2, s2);
    }
}

__device__ __forceinline__ float2 cs_of(float wv) {
    // angle = pi*tanh(wv); HW cos/sin take revolutions: tanh(wv)/2
    float e  = __builtin_amdgcn_exp2f((2.0f * LOG2E) * wv);
    float tt = 1.0f - 2.0f * __builtin_amdgcn_rcpf(e + 1.0f);
    float rv = 0.5f * tt;
    return make_float2(__builtin_amdgcn_cosf(rv), __builtin_amdgcn_sinf(rv));
}

// one thread computes BOTH pixels of its pair for angle l -> one b128 write
template <int G0, int LEN>
__device__ __forceinline__ void fill_cs(const float* __restrict__ Wm,
                                        const float* __restrict__ bvec,
                                        const float* xs, char* ldsbuf,
                                        int npr, int t) {
    for (int o = t; o < npr * LEN; o += NTHR) {
        int pr = (int)((unsigned)o / (unsigned)LEN);
        int l  = o - pr * LEN;
        int ch = 2 * CCH + G0 + l;
        float w0 = Wm[ch * 3 + 0], w1 = Wm[ch * 3 + 1], w2 = Wm[ch * 3 + 2];
        float bb = bvec[ch];
        int pa = 2 * pr, pb = 2 * pr + 1;       // npx always even
        float2 A = cs_of(fmaf(w0, xs[pa*3+0], fmaf(w1, xs[pa*3+1], w2 * xs[pa*3+2])) + bb);
        float2 B = cs_of(fmaf(w0, xs[pb*3+0], fmaf(w1, xs[pb*3+1], w2 * xs[pb*3+2])) + bb);
        float4 cell; cell.x = A.x; cell.y = B.x; cell.z = A.y; cell.w = B.y;
        *(float4*)(ldsbuf + pr * CSPAIR + l * 16) = cell;   // dense b128, no conflict
    }
}

__global__ __launch_bounds__(NTHR, 5) void gpd_kernel(
    const float* __restrict__ x,     // (4,3,64,64)
    const float* __restrict__ Wm,    // (629,3)
    const float* __restrict__ bvec,  // (629,)
    float* __restrict__ out)
{
    __shared__ alignas(16) char ldsbuf[NPR * VPX];     // 17136 B (cs | V overlay)
    __shared__ _Float16 lds_sh[PXB * CCH];             // s in f16
    __shared__ float xs[PXB * 3];

    const int t   = threadIdx.x;
    const int p0  = blockIdx.x * PXB;
    const int npx = min(PXB, NPIX - p0);               // always even
    const int npr = (npx + 1) >> 1;

    // ---- stage x into LDS ----
    for (int i = t; i < npx * 3; i += NTHR) {
        int px = (int)((unsigned)i / 3u); int c = i - px * 3;
        int p = p0 + px; int b = p >> 12; int hw = p & 4095;
        xs[i] = x[(b * 3 + c) * HWPIX + hw];
    }
    __syncthreads();

    // ---- A1: mean + s channels ----
    for (int o = t; o < npx * 68; o += NTHR) {
        int q = (int)((unsigned)o / 68u); int ch = o - q * 68;
        int p = p0 + q; int b = p >> 12; int hw = p & 4095;
        float wv = fmaf(Wm[ch*3+0], xs[q*3+0],
                   fmaf(Wm[ch*3+1], xs[q*3+1], Wm[ch*3+2] * xs[q*3+2])) + bvec[ch];
        if (ch < CCH) {
            out[(size_t)p * CCH + ch] = wv;                       // mean
        } else {
            float e  = __builtin_amdgcn_exp2f(-wv * LOG2E);
            float sg = __builtin_amdgcn_rcpf(1.0f + e);
            float sv = fmaf(999.999f, sg, 0.001f);                // s
            int c = ch - CCH;
            out[OFF_s + (size_t)(b * CCH + c) * HWPIX + hw] = sv;
            lds_sh[q * CCH + c] = (_Float16)sv;
        }
    }

    const int pr = t / CCH;
    const int m  = t - pr * CCH;
    const bool act = (t < npr * CCH);

    f32x2 R2[CCH];
    #pragma unroll
    for (int k = 0; k < CCH; ++k) { R2[k][0] = (k == m) ? 1.0f : 0.0f; R2[k][1] = R2[k][0]; }

    // ---- 4 chunks: fill cos/sin -> apply rotations ----
    fill_cs<0, 141>(Wm, bvec, xs, ldsbuf, npr, t);
    __syncthreads();
    if (act) apply_rots<0, 141>(R2, (const float4*)(ldsbuf + pr * CSPAIR));
    __syncthreads();
    fill_cs<141, 140>(Wm, bvec, xs, ldsbuf, npr, t);
    __syncthreads();
    if (act) apply_rots<141, 281>(R2, (const float4*)(ldsbuf + pr * CSPAIR));
    __syncthreads();
    fill_cs<281, 140>(Wm, bvec, xs, ldsbuf, npr, t);
    __syncthreads();
    if (act) apply_rots<281, 421>(R2, (const float4*)(ldsbuf + pr * CSPAIR));
    __syncthreads();
    fill_cs<421, 140>(Wm, bvec, xs, ldsbuf, npr, t);
    __syncthreads();
    if (act) apply_rots<421, 561>(R2, (const float4*)(ldsbuf + pr * CSPAIR));
    __syncthreads();

    // ---- pack R to f16 pairs once; R2 dies here (register pressure) ----
    h2 Rh[CCH];
    #pragma unroll
    for (int n = 0; n < CCH; ++n) {
#if __has_builtin(__builtin_amdgcn_cvt_pkrtz)
        Rh[n] = __builtin_bit_cast(h2, __builtin_amdgcn_cvt_pkrtz(R2[n][0], R2[n][1]));
#else
        h2 hv; hv[0] = (_Float16)R2[n][0]; hv[1] = (_Float16)R2[n][1]; Rh[n] = hv;
#endif
    }

    // ---- phase C in 2 rounds: stage V for 7 pixels (half h), compute S ----
    #pragma unroll
    for (int h = 0; h < 2; ++h) {
        if (act) {
            // V store: pairs of rows (2mp,2mp+1) packed per dword, thread m
            // writes half (m&1) of dword [(m>>1)*VROW + n] in region pr.
            char* base = ldsbuf + pr * VPX + (m >> 1) * (VROW * 4) + (m & 1) * 2;
            #pragma unroll
            for (int n = 0; n < CCH; ++n)
                *(_Float16*)(base + n * 4) = Rh[n][h];
        }
        __syncthreads();

        if (act) {
            const int px = 2 * pr + h;
            const unsigned* vb = (const unsigned*)(ldsbuf + pr * VPX);
            const _Float16* sh = lds_sh + px * CCH;
            float acc[CCH];
            #pragma unroll
            for (int n = 0; n < CCH; ++n) acc[n] = 0.0f;
            for (int mp = 0; mp < 17; ++mp) {
                const unsigned* row = vb + mp * VROW;
                h2 vk = __builtin_bit_cast(h2, row[m]) * *(const h2*)(sh + 2 * mp);
                #pragma unroll
                for (int g = 0; g < 8; ++g) {
                    uint4 rr = *(const uint4*)(row + 4 * g);
                    acc[4*g+0] = dot2h(vk, __builtin_bit_cast(h2, rr.x), acc[4*g+0]);
                    acc[4*g+1] = dot2h(vk, __builtin_bit_cast(h2, rr.y), acc[4*g+1]);
                    acc[4*g+2] = dot2h(vk, __builtin_bit_cast(h2, rr.z), acc[4*g+2]);
                    acc[4*g+3] = dot2h(vk, __builtin_bit_cast(h2, rr.w), acc[4*g+3]);
                }
                uint2 rr2 = *(const uint2*)(row + 32);
                acc[32] = dot2h(vk, __builtin_bit_cast(h2, rr2.x), acc[32]);
                acc[33] = dot2h(vk, __builtin_bit_cast(h2, rr2.y), acc[33]);
            }
            float* os = out + OFF_S + (size_t)(p0 + px) * (CCH * CCH) + m * CCH;
            #pragma unroll
            for (int n2 = 0; n2 < 17; ++n2) {
                float2 v; v.x = acc[2*n2]; v.y = acc[2*n2+1];
                *(float2*)(os + 2 * n2) = v;
            }
        }
        __syncthreads();        // region pr reused by round 2 / safe exit
    }
}

extern "C" void kernel_launch(void* const* d_in, const int* in_sizes, int n_in,
                              void* d_out, int out_size, void* d_ws, size_t ws_size,
                              hipStream_t stream) {
    const float* x  = (const float*)d_in[0];
    const float* W  = (const float*)d_in[1];
    const float* bv = (const float*)d_in[2];
    float* out = (float*)d_out;
    const int nblk = (NPIX + PXB - 1) / PXB;   // 1171
    hipLaunchKernelGGL(gpd_kernel, dim3(nblk), dim3(NTHR), 0, stream,
                       x, W, bv, out);
}